// Round 8
// baseline (673.199 us; speedup 1.0000x reference)
//
#include <hip/hip_runtime.h>

// MCH remap via a single L2-resident 16 B/cell record array:
//   cell k = v >> 13  (2^18 cells, mean Z/2^18 = 16 keys/cell)
//   rec[k] = { base  = lower_bound(table[:m], k<<13)   (exact, 32-bit)
//              sig   = 96-bit Bloom of the cell's keys (4 bits/key into one
//                      hash-selected 32-bit word; fp ~5.6%) }
// Records are exactly 4 MB -> fit one XCD's L2. Negative path (~94% of
// elements, hit rate is Z/2^31 ~ 0.2%) = ONE 16 B L2-hit load. Positive
// path resolves exactly by scanning table quads from base (nontemporal,
// so the scan does not evict records):
//   invariants (any sorted table): entries < base are < k<<13 <= v (counted
//   as "< v"); entries of later cells are > v; so ans = s + #{< v from s},
//   eq detects presence of v; loop breaks at the first quad whose max >= v
//   (exists in-bounds or the scalar tail to z terminates).
// Build is atomic-free: O(z) boundary scatter -> per-cell sequential scan.

#define CELL_BITS 18
#define CELL_SH   (31 - CELL_BITS)          // 13
#define NCELL     (1u << CELL_BITS)         // 262144
#define AUXN      (NCELL + 1u)

typedef int vint4 __attribute__((ext_vector_type(4)));

__device__ __forceinline__ void hash4(unsigned v, int* sel, unsigned* mask) {
    unsigned h1 = v * 2654435761u;          // 4 bit positions from bits 0..19
    unsigned h2 = v * 0x85EBCA6Bu;
    *mask = (1u << (h1 & 31)) | (1u << ((h1 >> 5) & 31)) |
            (1u << ((h1 >> 10) & 31)) | (1u << ((h1 >> 15) & 31));
    *sel = (int)(((h2 >> 16) * 3u) >> 16);  // uniform in {0,1,2}
}

// ---- build 1: aux[k] = lower_bound(table[:m], k<<SH), O(z) scatter ----
__global__ __launch_bounds__(256) void build_aux_scatter(
    const int* __restrict__ table, int m, int* __restrict__ aux) {
    int j = blockIdx.x * blockDim.x + threadIdx.x;
    if (j >= m) return;
    unsigned lo_k = (j == 0) ? 0u : ((((unsigned)table[j - 1]) >> CELL_SH) + 1u);
    unsigned hi_k = ((unsigned)table[j]) >> CELL_SH;
    for (unsigned k = lo_k; k <= hi_k; ++k) aux[k] = j;
    if (j == m - 1) {
        for (unsigned k = hi_k + 1; k <= NCELL; ++k) aux[k] = m;
    }
}

// ---- build 2: per-cell {base, sig96}, sequential reads, plain store ----
__global__ __launch_bounds__(256) void build_records(
    const int* __restrict__ table, const int* __restrict__ aux, int z,
    vint4* __restrict__ rec) {
    unsigned k = blockIdx.x * blockDim.x + threadIdx.x;
    if (k >= NCELL) return;
    int base = aux[k];
    unsigned s0 = 0, s1 = 0, s2 = 0;
    int p = base;
    while (p < z) {
        unsigned tv = (unsigned)__builtin_nontemporal_load(table + p);
        if ((tv >> CELL_SH) != k) break;    // covers index m too (scan over [:z])
        int sel; unsigned mk;
        hash4(tv, &sel, &mk);
        s0 |= (sel == 0) ? mk : 0u;
        s1 |= (sel == 1) ? mk : 0u;
        s2 |= (sel == 2) ? mk : 0u;
        ++p;
    }
    vint4 r;
    r.x = base; r.y = (int)s0; r.z = (int)s1; r.w = (int)s2;
    rec[k] = r;
}

// ---- exact resolution from base (positive lanes only, ~6%) ----
__device__ __forceinline__ int resolve_from_base(
    int v, int base, const int* __restrict__ table,
    const int* __restrict__ mapping, int z, int zch) {
    int s = base & ~3;
    int cnt = 0;
    bool eq = false;
    int p = s;
    for (;;) {
        if (p + 4 <= z) {
            int tx = __builtin_nontemporal_load(table + p);
            int ty = __builtin_nontemporal_load(table + p + 1);
            int tz = __builtin_nontemporal_load(table + p + 2);
            int tw = __builtin_nontemporal_load(table + p + 3);
            cnt += (tx < v) + (ty < v) + (tz < v) + (tw < v);
            eq = eq | (tx == v) | (ty == v) | (tz == v) | (tw == v);
            p += 4;
            if (tw >= v) break;             // sorted: first >= v seen
        } else {
            for (; p < z; ++p) {
                int t = __builtin_nontemporal_load(table + p);
                cnt += (t < v);
                eq = eq | (t == v);
            }
            break;
        }
    }
    return eq ? __builtin_nontemporal_load(mapping + (s + cnt)) : zch;
}

// ---- main: 8 values/thread; one 16 B record probe per value ----
__global__ __launch_bounds__(256) void mch_remap_rec_kernel(
    const vint4* __restrict__ values4,
    const int* __restrict__ table,
    const int* __restrict__ mapping,
    const int* __restrict__ zch_p,
    const vint4* __restrict__ rec,
    vint4* __restrict__ out4,
    int half4, int z) {

    int zch = *zch_p;
    int i = blockIdx.x * blockDim.x + threadIdx.x;
    if (i >= half4) return;

    vint4 va = __builtin_nontemporal_load(values4 + i);
    vint4 vb = __builtin_nontemporal_load(values4 + i + half4);
    int v[8] = {va.x, va.y, va.z, va.w, vb.x, vb.y, vb.z, vb.w};

    vint4 r[8];
#pragma unroll
    for (int e = 0; e < 8; ++e) r[e] = rec[((unsigned)v[e]) >> CELL_SH];

    int res[8];
#pragma unroll
    for (int e = 0; e < 8; ++e) {
        int sel; unsigned mk;
        hash4((unsigned)v[e], &sel, &mk);
        unsigned w = (sel == 0) ? (unsigned)r[e].y
                   : (sel == 1) ? (unsigned)r[e].z
                                : (unsigned)r[e].w;
        bool maybe = (w & mk) == mk;        // ~6% of lanes
        res[e] = maybe
                     ? resolve_from_base(v[e], r[e].x, table, mapping, z, zch)
                     : zch;
    }
    vint4 oa, ob;
    oa.x = res[0]; oa.y = res[1]; oa.z = res[2]; oa.w = res[3];
    ob.x = res[4]; ob.y = res[5]; ob.z = res[6]; ob.w = res[7];
    __builtin_nontemporal_store(oa, out4 + i);
    __builtin_nontemporal_store(ob, out4 + i + half4);
}

// scalar tail (n % 8 != 0)
__global__ __launch_bounds__(64) void mch_remap_tail_kernel(
    const int* __restrict__ values, const int* __restrict__ table,
    const int* __restrict__ mapping, const int* __restrict__ zch_p,
    const vint4* __restrict__ rec, int* __restrict__ out,
    int start, int n, int z) {
    int i = start + blockIdx.x * blockDim.x + threadIdx.x;
    if (i >= n) return;
    int v = values[i];
    vint4 r = rec[((unsigned)v) >> CELL_SH];
    int sel; unsigned mk;
    hash4((unsigned)v, &sel, &mk);
    unsigned w = (sel == 0) ? (unsigned)r.y
               : (sel == 1) ? (unsigned)r.z : (unsigned)r.w;
    int zch = *zch_p;
    out[i] = ((w & mk) == mk)
                 ? resolve_from_base(v, r.x, table, mapping, z, zch) : zch;
}

// ---- fallback (aux-window count) if ws is too small for records ----
__global__ __launch_bounds__(256) void mch_remap_aux_kernel(
    const int* __restrict__ values, const int* __restrict__ table,
    const int* __restrict__ mapping, const int* __restrict__ zch_p,
    const int* __restrict__ aux, int* __restrict__ out, int n, int z) {
    int zch = *zch_p;
    int i = blockIdx.x * blockDim.x + threadIdx.x;
    if (i >= n) return;
    int v = __builtin_nontemporal_load(values + i);
    unsigned k = ((unsigned)v) >> CELL_SH;
    int lo = aux[k];
    int hi = aux[k + 1];
    int s = lo & ~3;
    int e = (hi + 3) & ~3;
    if (e > z) e = z;
    int cnt = 0;
    bool eq = false;
    for (int p = s; p < e; p += 4) {
        int4 t = *(const int4*)(table + p);
        cnt += (t.x < v) + (t.y < v) + (t.z < v) + (t.w < v);
        eq = eq | (t.x == v) | (t.y == v) | (t.z == v) | (t.w == v);
    }
    out[i] = eq ? mapping[s + cnt] : zch;
}

extern "C" void kernel_launch(void* const* d_in, const int* in_sizes, int n_in,
                              void* d_out, int out_size, void* d_ws, size_t ws_size,
                              hipStream_t stream) {
    const int* values  = (const int*)d_in[0];
    const int* table   = (const int*)d_in[1];
    const int* mapping = (const int*)d_in[2];
    const int* zch_p   = (const int*)d_in[3];
    int* out = (int*)d_out;

    int n = in_sizes[0];          // 33_554_432
    int z = in_sizes[1];          // 4_194_304
    int m = z - 1;

    size_t rec_bytes = (size_t)NCELL * 16;              // 4 MB
    size_t aux_bytes = (size_t)AUXN * sizeof(int);      // 1 MB
    int block = 256;

    if (ws_size >= rec_bytes + aux_bytes) {
        vint4* rec = (vint4*)d_ws;
        int*   aux = (int*)((char*)d_ws + rec_bytes);

        build_aux_scatter<<<(m + block - 1) / block, block, 0, stream>>>(
            table, m, aux);
        build_records<<<(NCELL + block - 1) / block, block, 0, stream>>>(
            table, aux, z, rec);

        int half4 = n >> 3;                  // int4 units per segment
        if (half4 > 0) {
            mch_remap_rec_kernel<<<(half4 + block - 1) / block, block, 0, stream>>>(
                (const vint4*)values, table, mapping, zch_p, rec,
                (vint4*)out, half4, z);
        }
        int done = (half4 << 3);
        if (done < n) {
            mch_remap_tail_kernel<<<((n - done) + 63) / 64, 64, 0, stream>>>(
                values, table, mapping, zch_p, rec, out, done, n, z);
        }
    } else if (ws_size >= aux_bytes) {
        int* aux = (int*)d_ws;
        build_aux_scatter<<<(m + block - 1) / block, block, 0, stream>>>(
            table, m, aux);
        mch_remap_aux_kernel<<<(n + block - 1) / block, block, 0, stream>>>(
            values, table, mapping, zch_p, aux, out, n, z);
    }
}